// Round 10
// baseline (5296.124 us; speedup 1.0000x reference)
//
#include <hip/hip_runtime.h>
#include <hip/hip_bf16.h>

// ---------------------------------------------------------------------------
// Sparse 3-level U-Net. ALL tensors float32 (probe-verified: d_out is f32,
// reference is pure f32 — prior rounds' bf16 reads were the entire failure).
// f32 compute, f64 BN stats (deterministic two-pass), BN+relu fused into the
// gather of every consumer conv; concat BNs/convs split channel-separably.
// Arena (~126 MB) probe-verified to fit ws_size; part/ab tail placed first.
// ---------------------------------------------------------------------------

// Gather conv (sm-conv K=27 or down-conv K=8):
//   out[r,c] (+=) sum_k sum_ci relu(BN(feat[nbr[r,k], ci])) * W[k, ci+cioff, c]
// W rows are WROW wide (full weight CIN). Block T=COUT*TR threads,
// RB=TR*ACC rows/block, ACC accumulators/thread.
template<int CIN, int COUT, int K, int TR, int ACC, int WROW, bool FUSEBN, bool ACCUM>
__global__ void gconv(const float* __restrict__ feat, const int* __restrict__ nbr,
                      const float* __restrict__ W, int cioff,
                      const float* __restrict__ ab, float* __restrict__ out, int N) {
    constexpr int T  = COUT * TR;
    constexpr int RB = TR * ACC;
    __shared__ float sW[CIN * COUT];
    __shared__ float sF[RB * CIN];
    __shared__ int   sIdx[RB];
    __shared__ float sA[FUSEBN ? CIN : 1];
    __shared__ float sB[FUSEBN ? CIN : 1];
    const int tid = threadIdx.x;
    const int c   = tid % COUT;
    const int r0  = tid / COUT;
    const long long row0 = (long long)blockIdx.x * RB;
    if (FUSEBN && tid < CIN) { sA[tid] = ab[tid]; sB[tid] = ab[CIN + tid]; }
    float acc[ACC];
#pragma unroll
    for (int a = 0; a < ACC; a++) acc[a] = 0.f;

    for (int k = 0; k < K; k++) {
        __syncthreads();  // protects prior-iter sF/sW reads and the sA/sB init
        if (tid < RB) {
            long long r = row0 + tid;
            sIdx[tid] = (r < N) ? nbr[r * K + k] : -1;
        }
        for (int e = tid; e < CIN * COUT; e += T) {
            int ci = e / COUT, cc = e - ci * COUT;
            sW[e] = W[((long long)k * WROW + ci + cioff) * COUT + cc];
        }
        __syncthreads();
        for (int e = tid; e < RB * CIN; e += T) {
            int r = e / CIN, ci = e - r * CIN;
            long long idx = sIdx[r];
            float v = 0.f;
            if (idx >= 0) {
                v = feat[idx * CIN + ci];
                if (FUSEBN) { v = v * sA[ci] + sB[ci]; v = v > 0.f ? v : 0.f; }
            }
            sF[e] = v;
        }
        __syncthreads();
#pragma unroll 4
        for (int ci = 0; ci < CIN; ci++) {
            float w = sW[ci * COUT + c];
#pragma unroll
            for (int a = 0; a < ACC; a++)
                acc[a] += sF[(r0 + a * TR) * CIN + ci] * w;
        }
    }
#pragma unroll
    for (int a = 0; a < ACC; a++) {
        long long r = row0 + r0 + a * TR;
        if (r < N) {
            float* p = &out[r * COUT + c];
            *p = ACCUM ? (*p + acc[a]) : acc[a];
        }
    }
}

// Transposed (up) conv: coarse row i, octant k, child idx>=0:
//   out[idx, c] = sum_ci relu(BN(featc[i,ci])) * W[k,ci,c]
// Scatter is a permutation of fine rows -> plain stores, full coverage.
template<int CIN, int COUT, int TR>
__global__ void upconv(const float* __restrict__ featc, const int* __restrict__ rb,
                       const float* __restrict__ W, const float* __restrict__ ab,
                       float* __restrict__ out, int N) {
    constexpr int K = 8;
    constexpr int T = COUT * TR;
    __shared__ float sW[CIN * COUT];
    __shared__ float sF[TR * CIN];
    __shared__ float sA[CIN];
    __shared__ float sB[CIN];
    const int tid = threadIdx.x;
    const int c   = tid % COUT;
    const int r0  = tid / COUT;
    const long long row = (long long)blockIdx.x * TR + r0;
    if (tid < CIN) { sA[tid] = ab[tid]; sB[tid] = ab[CIN + tid]; }
    __syncthreads();
    for (int e = tid; e < TR * CIN; e += T) {
        int r = e / CIN, ci = e - r * CIN;
        long long rr = (long long)blockIdx.x * TR + r;
        float v = 0.f;
        if (rr < N) {
            v = featc[rr * CIN + ci];
            v = v * sA[ci] + sB[ci];
            v = v > 0.f ? v : 0.f;
        }
        sF[e] = v;
    }
    for (int k = 0; k < K; k++) {
        __syncthreads();
        for (int e = tid; e < CIN * COUT; e += T)
            sW[e] = W[(long long)k * CIN * COUT + e];
        __syncthreads();
        long long idx = (row < N) ? rb[row * K + k] : -1;
        if (idx >= 0) {
            float a = 0.f;
#pragma unroll 4
            for (int ci = 0; ci < CIN; ci++)
                a += sF[r0 * CIN + ci] * sW[ci * COUT + c];
            out[idx * COUT + c] = a;
        }
    }
}

// BN stats pass 1: per-block f64 partial sum/sumsq per channel, deterministic.
// part[b*256 + c] = sum, part[b*256 + 128 + c] = sumsq.
template<int C>
__global__ void bn_stats(const float* __restrict__ x, double* __restrict__ part, int N) {
    constexpr int RPB = 256 / C;
    __shared__ double ls[256], lq[256];
    const int tid = threadIdx.x;
    double s = 0.0, q = 0.0;
    if (tid < RPB * C) {
        const int c  = tid % C;
        const int rr = tid / C;
        for (long long r = (long long)blockIdx.x * RPB + rr; r < N;
             r += (long long)gridDim.x * RPB) {
            double v = (double)x[r * C + c];
            s += v; q += v * v;
        }
    }
    ls[tid] = s; lq[tid] = q;
    __syncthreads();
    if (tid < C) {
        for (int j = 1; j < RPB; j++) { s += ls[j * C + tid]; q += lq[j * C + tid]; }
        part[blockIdx.x * 256 + tid]       = s;
        part[blockIdx.x * 256 + 128 + tid] = q;
    }
}

// BN stats pass 2 (f64): a = gamma/sqrt(var+eps), b = beta - mu*a.
// gamma = gb[goff+c], beta = gb[gbfull+goff+c] (handles concat-slice BNs).
__global__ void bn_fin(const double* __restrict__ part, const float* __restrict__ gb,
                       int gbfull, int goff, float* __restrict__ ab,
                       int C, int P, double invN) {
    int c = threadIdx.x;
    if (c >= C) return;
    double s = 0.0, q = 0.0;
    for (int p = 0; p < P; p++) { s += part[p * 256 + c]; q += part[p * 256 + 128 + c]; }
    double mu  = s * invN;
    double var = q * invN - mu * mu;
    double a   = (double)gb[goff + c] / sqrt(var + 1e-4);
    ab[c]     = (float)a;
    ab[C + c] = (float)((double)gb[gbfull + goff + c] - mu * a);
}

// out[r,:2] = relu(y0*a+b) @ lin_w + lin_b (bnf fused). f32 stores.
__global__ void final_k(const float* __restrict__ x, const float* __restrict__ ab,
                        const float* __restrict__ lw, const float* __restrict__ lb,
                        float* __restrict__ out, int N) {
    long long r = (long long)blockIdx.x * blockDim.x + threadIdx.x;
    if (r >= N) return;
    float a0 = lb[0], a1 = lb[1];
#pragma unroll
    for (int ci = 0; ci < 32; ci++) {
        float v = x[r * 32 + ci] * ab[ci] + ab[32 + ci];
        v = v > 0.f ? v : 0.f;
        a0 += v * lw[ci * 2];
        a1 += v * lw[ci * 2 + 1];
    }
    out[2 * r]     = a0;
    out[2 * r + 1] = a1;
}

extern "C" void kernel_launch(void* const* d_in, const int* in_sizes, int n_in,
                              void* d_out, int out_size, void* d_ws, size_t ws_size,
                              hipStream_t stream) {
    const long long N0 = in_sizes[0] / 3;
    const long long N1 = in_sizes[26] / 8;
    const long long N2 = in_sizes[27] / 8;
    const int P = 64;

    const float* feat = (const float*)d_in[0];
    const int* nbr0 = (const int*)d_in[23];
    const int* nbr1 = (const int*)d_in[24];
    const int* nbr2 = (const int*)d_in[25];
    const int* rb0  = (const int*)d_in[26];
    const int* rb1  = (const int*)d_in[27];

    // ---- arena: small critical tail first, then lifetime-reused slots ----
    double* part = (double*)d_ws;                        // 64*256 f64 = 128 KB
    float*  ab   = (float*)(part + (long long)P * 256);  // 12 * 256 f32
    float*  base = ab + 12 * 256;
    long long szBig = N0 * 32;
    if (N1 * 64 > szBig) szBig = N1 * 64;
    if (N2 * 96 > szBig) szBig = N2 * 96;
    long long szD = (N1 * 64 > N2 * 96) ? N1 * 64 : N2 * 96;
    float* D = base;            // x2 (N2x96), y1 (N1x64)
    float* A = D + szD;         // t0, d0, d1, u1, u0
    float* B = A + szBig;       // x0 skip (N0x32)
    float* C = B + N0 * 32;     // x1 (N1x64), y0 (N0x32)

#define STATS(CH, X, NN) bn_stats<CH><<<P, 256, 0, stream>>>(X, part, (int)(NN))
#define FIN(GBI, GBFULL, GOFF, SL, CH, NN)                                           \
    bn_fin<<<1, CH, 0, stream>>>(part, (const float*)d_in[GBI], GBFULL, GOFF,        \
                                 ab + (SL) * 256, CH, P, 1.0 / (double)(NN))
#define AB(SL) (ab + (SL) * 256)
#define WF(I) ((const float*)d_in[I])

    // ---- level 0 ----
    gconv<3, 32, 27, 8, 4, 3, false, false><<<(int)((N0 + 31) / 32), 256, 0, stream>>>(
        feat, nbr0, WF(1), 0, nullptr, A, (int)N0);                       // t0 -> A
    STATS(32, A, N0); FIN(2, 32, 0, 0, 32, N0);                           // bn1_0
    gconv<32, 32, 27, 8, 4, 32, true, false><<<(int)((N0 + 31) / 32), 256, 0, stream>>>(
        A, nbr0, WF(3), 0, AB(0), B, (int)N0);                            // x0 -> B
    STATS(32, B, N0); FIN(4, 32, 0, 1, 32, N0);                           // bnd_0
    gconv<32, 64, 8, 4, 4, 32, true, false><<<(int)((N1 + 15) / 16), 256, 0, stream>>>(
        B, rb0, WF(5), 0, AB(1), A, (int)N1);                             // d0 -> A

    // ---- level 1 ----
    STATS(64, A, N1); FIN(6, 64, 0, 2, 64, N1);                           // bn1_1
    gconv<64, 64, 27, 4, 4, 64, true, false><<<(int)((N1 + 15) / 16), 256, 0, stream>>>(
        A, nbr1, WF(7), 0, AB(2), C, (int)N1);                            // x1 -> C
    STATS(64, C, N1); FIN(8, 64, 0, 3, 64, N1);                           // bnd_1
    gconv<64, 96, 8, 2, 4, 64, true, false><<<(int)((N2 + 7) / 8), 192, 0, stream>>>(
        C, rb1, WF(9), 0, AB(3), A, (int)N2);                             // d1 -> A

    // ---- level 2 ----
    STATS(96, A, N2); FIN(10, 96, 0, 4, 96, N2);                          // bn1_2
    gconv<96, 96, 27, 2, 4, 96, true, false><<<(int)((N2 + 7) / 8), 192, 0, stream>>>(
        A, nbr2, WF(11), 0, AB(4), D, (int)N2);                           // x2 -> D
    STATS(96, D, N2); FIN(12, 96, 0, 5, 96, N2);                          // bnu_1

    // ---- up to level 1 (concat handled channel-separably) ----
    upconv<96, 64, 4><<<(int)((N2 + 3) / 4), 256, 0, stream>>>(
        D, rb1, WF(13), AB(5), A, (int)N2);                               // u1 -> A
    STATS(64, C, N1); FIN(14, 128, 0, 6, 64, N1);                         // bn2_1 [x1 half]
    STATS(64, A, N1); FIN(14, 128, 64, 7, 64, N1);                        // bn2_1 [u1 half]
    gconv<64, 64, 27, 4, 4, 128, true, false><<<(int)((N1 + 15) / 16), 256, 0, stream>>>(
        C, nbr1, WF(15), 0, AB(6), D, (int)N1);                           // y1 p1 -> D
    gconv<64, 64, 27, 4, 4, 128, true, true><<<(int)((N1 + 15) / 16), 256, 0, stream>>>(
        A, nbr1, WF(15), 64, AB(7), D, (int)N1);                          // y1 += p2
    STATS(64, D, N1); FIN(16, 64, 0, 8, 64, N1);                          // bnu_0

    // ---- up to level 0 ----
    upconv<64, 32, 8><<<(int)((N1 + 7) / 8), 256, 0, stream>>>(
        D, rb0, WF(17), AB(8), A, (int)N1);                               // u0 -> A
    STATS(32, B, N0); FIN(18, 64, 0, 9, 32, N0);                          // bn2_0 [x0 half]
    STATS(32, A, N0); FIN(18, 64, 32, 10, 32, N0);                        // bn2_0 [u0 half]
    gconv<32, 32, 27, 8, 4, 64, true, false><<<(int)((N0 + 31) / 32), 256, 0, stream>>>(
        B, nbr0, WF(19), 0, AB(9), C, (int)N0);                           // y0 p1 -> C
    gconv<32, 32, 27, 8, 4, 64, true, true><<<(int)((N0 + 31) / 32), 256, 0, stream>>>(
        A, nbr0, WF(19), 32, AB(10), C, (int)N0);                         // y0 += p2
    STATS(32, C, N0); FIN(20, 32, 0, 11, 32, N0);                         // bnf

    final_k<<<(int)((N0 + 255) / 256), 256, 0, stream>>>(
        C, AB(11), WF(21), WF(22), (float*)d_out, (int)N0);

#undef STATS
#undef FIN
#undef AB
#undef WF
}

// Round 11
// 3339.260 us; speedup vs baseline: 1.5860x; 1.5860x over previous
//
#include <hip/hip_runtime.h>
#include <hip/hip_bf16.h>

// ---------------------------------------------------------------------------
// Sparse 3-level U-Net, all-f32, f64 BN stats. Round 11: 2D-register-blocked
// gconv2 (4x4 tile/thread, transposed LDS feature tile, b128 reads) for the
// five 27-tap convs + d0; bn_stats grid 64->256. Baseline R10: 5296 us.
// ---------------------------------------------------------------------------

// ---------- old-style gather conv (kept for t0 CIN=3 and d1 64->96) --------
template<int CIN, int COUT, int K, int TR, int ACC, int WROW, bool FUSEBN, bool ACCUM>
__global__ void gconv(const float* __restrict__ feat, const int* __restrict__ nbr,
                      const float* __restrict__ W, int cioff,
                      const float* __restrict__ ab, float* __restrict__ out, int N) {
    constexpr int T  = COUT * TR;
    constexpr int RB = TR * ACC;
    __shared__ float sW[CIN * COUT];
    __shared__ float sF[RB * CIN];
    __shared__ int   sIdx[RB];
    __shared__ float sA[FUSEBN ? CIN : 1];
    __shared__ float sB[FUSEBN ? CIN : 1];
    const int tid = threadIdx.x;
    const int c   = tid % COUT;
    const int r0  = tid / COUT;
    const long long row0 = (long long)blockIdx.x * RB;
    if (FUSEBN && tid < CIN) { sA[tid] = ab[tid]; sB[tid] = ab[CIN + tid]; }
    float acc[ACC];
#pragma unroll
    for (int a = 0; a < ACC; a++) acc[a] = 0.f;

    for (int k = 0; k < K; k++) {
        __syncthreads();
        if (tid < RB) {
            long long r = row0 + tid;
            sIdx[tid] = (r < N) ? nbr[r * K + k] : -1;
        }
        for (int e = tid; e < CIN * COUT; e += T) {
            int ci = e / COUT, cc = e - ci * COUT;
            sW[e] = W[((long long)k * WROW + ci + cioff) * COUT + cc];
        }
        __syncthreads();
        for (int e = tid; e < RB * CIN; e += T) {
            int r = e / CIN, ci = e - r * CIN;
            long long idx = sIdx[r];
            float v = 0.f;
            if (idx >= 0) {
                v = feat[idx * CIN + ci];
                if (FUSEBN) { v = v * sA[ci] + sB[ci]; v = v > 0.f ? v : 0.f; }
            }
            sF[e] = v;
        }
        __syncthreads();
#pragma unroll 4
        for (int ci = 0; ci < CIN; ci++) {
            float w = sW[ci * COUT + c];
#pragma unroll
            for (int a = 0; a < ACC; a++)
                acc[a] += sF[(r0 + a * TR) * CIN + ci] * w;
        }
    }
#pragma unroll
    for (int a = 0; a < ACC; a++) {
        long long r = row0 + r0 + a * TR;
        if (r < N) {
            float* p = &out[r * COUT + c];
            *p = ACCUM ? (*p + acc[a]) : acc[a];
        }
    }
}

// ---------- NEW: 2D-register-blocked gather conv ---------------------------
// Thread owns a 4x4 (row x col) output tile. LDS: sW=[ci][cout] (b128 rows),
// sF=[ci][row] transposed, stride BR+4 (2-way banks, 16B aligned). BN+relu
// fused at gather (coeffs in registers). 2 syncthreads per k.
template<int CIN, int COUT, int BR, int K, int TPB, int WROW, bool ACCUM>
__global__ __launch_bounds__(TPB) void gconv2(
    const float* __restrict__ feat, const int* __restrict__ nbr,
    const float* __restrict__ W, int cioff,
    const float* __restrict__ ab, float* __restrict__ out, int N) {
    constexpr int CG  = COUT / 4;
    constexpr int RG  = BR / 4;
    static_assert(CG * RG == TPB, "tile/thread mismatch");
    constexpr int TPR = TPB / BR;       // staging threads per row
    constexpr int CPT = CIN / TPR;      // staging ci per thread
    static_assert(TPR * BR == TPB && CPT * TPR == CIN && CPT % 4 == 0, "staging");
    constexpr int SFS = BR + 4;         // sF row stride (padded, mult of 4)
    __shared__ float sW[CIN * COUT];
    __shared__ float sF[CIN * SFS];
    const int tid  = threadIdx.x;
    const int cg   = tid % CG;
    const int rg   = tid / CG;
    const int sr   = tid % BR;                 // staging row
    const int scio = (tid / BR) * CPT;         // staging ci offset
    const long long row0 = (long long)blockIdx.x * BR;

    float ba[CPT], bb[CPT];
#pragma unroll
    for (int j = 0; j < CPT; j++) { ba[j] = ab[scio + j]; bb[j] = ab[CIN + scio + j]; }

    float acc[4][4];
#pragma unroll
    for (int i = 0; i < 4; i++)
#pragma unroll
        for (int l = 0; l < 4; l++) acc[i][l] = 0.f;

    const long long srow = row0 + sr;

    for (int k = 0; k < K; k++) {
        __syncthreads();   // protect prior-iteration sW/sF reads
        // stage weights (row-wise float4; COUT%4==0 so chunks never cross rows)
        for (int e = tid * 4; e < CIN * COUT; e += TPB * 4) {
            int ci = e / COUT, cc = e - ci * COUT;
            float4 v = *reinterpret_cast<const float4*>(
                W + ((long long)k * WROW + ci + cioff) * COUT + cc);
            *reinterpret_cast<float4*>(sW + e) = v;
        }
        // stage features (gather + BN + relu), transposed into sF[ci][row]
        {
            int idx = (srow < N) ? nbr[srow * K + k] : -1;
            if (idx >= 0) {
                const float* fr = feat + (long long)idx * CIN + scio;
#pragma unroll
                for (int j = 0; j < CPT; j += 4) {
                    float4 v = *reinterpret_cast<const float4*>(fr + j);
                    float t0 = v.x * ba[j]     + bb[j];
                    float t1 = v.y * ba[j + 1] + bb[j + 1];
                    float t2 = v.z * ba[j + 2] + bb[j + 2];
                    float t3 = v.w * ba[j + 3] + bb[j + 3];
                    sF[(scio + j)     * SFS + sr] = t0 > 0.f ? t0 : 0.f;
                    sF[(scio + j + 1) * SFS + sr] = t1 > 0.f ? t1 : 0.f;
                    sF[(scio + j + 2) * SFS + sr] = t2 > 0.f ? t2 : 0.f;
                    sF[(scio + j + 3) * SFS + sr] = t3 > 0.f ? t3 : 0.f;
                }
            } else {
#pragma unroll
                for (int j = 0; j < CPT; j++) sF[(scio + j) * SFS + sr] = 0.f;
            }
        }
        __syncthreads();
        // inner: per 4-ci chunk, 8 x b128 LDS + 64 FMA
#pragma unroll 4
        for (int ci = 0; ci < CIN; ci += 4) {
#pragma unroll
            for (int j = 0; j < 4; j++) {
                float4 wv = *reinterpret_cast<const float4*>(sW + (ci + j) * COUT + 4 * cg);
                float4 fv = *reinterpret_cast<const float4*>(sF + (ci + j) * SFS + 4 * rg);
                const float wq[4] = {wv.x, wv.y, wv.z, wv.w};
                const float fq[4] = {fv.x, fv.y, fv.z, fv.w};
#pragma unroll
                for (int i = 0; i < 4; i++)
#pragma unroll
                    for (int l = 0; l < 4; l++)
                        acc[i][l] = fmaf(fq[i], wq[l], acc[i][l]);
            }
        }
    }
    // store 4x4 tile (float4 per row)
#pragma unroll
    for (int i = 0; i < 4; i++) {
        long long r = row0 + 4 * rg + i;
        if (r < N) {
            float* p = out + r * COUT + 4 * cg;
            if (ACCUM) {
                float4 o = *reinterpret_cast<float4*>(p);
                o.x += acc[i][0]; o.y += acc[i][1]; o.z += acc[i][2]; o.w += acc[i][3];
                *reinterpret_cast<float4*>(p) = o;
            } else {
                *reinterpret_cast<float4*>(p) =
                    make_float4(acc[i][0], acc[i][1], acc[i][2], acc[i][3]);
            }
        }
    }
}

// ---------- transposed (up) conv: permutation scatter ----------------------
template<int CIN, int COUT, int TR>
__global__ void upconv(const float* __restrict__ featc, const int* __restrict__ rb,
                       const float* __restrict__ W, const float* __restrict__ ab,
                       float* __restrict__ out, int N) {
    constexpr int K = 8;
    constexpr int T = COUT * TR;
    __shared__ float sW[CIN * COUT];
    __shared__ float sF[TR * CIN];
    __shared__ float sA[CIN];
    __shared__ float sB[CIN];
    const int tid = threadIdx.x;
    const int c   = tid % COUT;
    const int r0  = tid / COUT;
    const long long row = (long long)blockIdx.x * TR + r0;
    if (tid < CIN) { sA[tid] = ab[tid]; sB[tid] = ab[CIN + tid]; }
    __syncthreads();
    for (int e = tid; e < TR * CIN; e += T) {
        int r = e / CIN, ci = e - r * CIN;
        long long rr = (long long)blockIdx.x * TR + r;
        float v = 0.f;
        if (rr < N) {
            v = featc[rr * CIN + ci];
            v = v * sA[ci] + sB[ci];
            v = v > 0.f ? v : 0.f;
        }
        sF[e] = v;
    }
    for (int k = 0; k < K; k++) {
        __syncthreads();
        for (int e = tid; e < CIN * COUT; e += T)
            sW[e] = W[(long long)k * CIN * COUT + e];
        __syncthreads();
        long long idx = (row < N) ? rb[row * K + k] : -1;
        if (idx >= 0) {
            float a = 0.f;
#pragma unroll 4
            for (int ci = 0; ci < CIN; ci++)
                a += sF[r0 * CIN + ci] * sW[ci * COUT + c];
            out[idx * COUT + c] = a;
        }
    }
}

// ---------- BN stats (two-pass, deterministic, f64) ------------------------
template<int C>
__global__ void bn_stats(const float* __restrict__ x, double* __restrict__ part, int N) {
    constexpr int RPB = 256 / C;
    __shared__ double ls[256], lq[256];
    const int tid = threadIdx.x;
    double s = 0.0, q = 0.0;
    if (tid < RPB * C) {
        const int c  = tid % C;
        const int rr = tid / C;
        for (long long r = (long long)blockIdx.x * RPB + rr; r < N;
             r += (long long)gridDim.x * RPB) {
            double v = (double)x[r * C + c];
            s += v; q += v * v;
        }
    }
    ls[tid] = s; lq[tid] = q;
    __syncthreads();
    if (tid < C) {
        for (int j = 1; j < RPB; j++) { s += ls[j * C + tid]; q += lq[j * C + tid]; }
        part[blockIdx.x * 256 + tid]       = s;
        part[blockIdx.x * 256 + 128 + tid] = q;
    }
}

__global__ void bn_fin(const double* __restrict__ part, const float* __restrict__ gb,
                       int gbfull, int goff, float* __restrict__ ab,
                       int C, int P, double invN) {
    int c = threadIdx.x;
    if (c >= C) return;
    double s = 0.0, q = 0.0;
    for (int p = 0; p < P; p++) { s += part[p * 256 + c]; q += part[p * 256 + 128 + c]; }
    double mu  = s * invN;
    double var = q * invN - mu * mu;
    double a   = (double)gb[goff + c] / sqrt(var + 1e-4);
    ab[c]     = (float)a;
    ab[C + c] = (float)((double)gb[gbfull + goff + c] - mu * a);
}

// ---------- final linear (bnf fused) ---------------------------------------
__global__ void final_k(const float* __restrict__ x, const float* __restrict__ ab,
                        const float* __restrict__ lw, const float* __restrict__ lb,
                        float* __restrict__ out, int N) {
    long long r = (long long)blockIdx.x * blockDim.x + threadIdx.x;
    if (r >= N) return;
    float a0 = lb[0], a1 = lb[1];
#pragma unroll
    for (int ci = 0; ci < 32; ci++) {
        float v = x[r * 32 + ci] * ab[ci] + ab[32 + ci];
        v = v > 0.f ? v : 0.f;
        a0 += v * lw[ci * 2];
        a1 += v * lw[ci * 2 + 1];
    }
    out[2 * r]     = a0;
    out[2 * r + 1] = a1;
}

extern "C" void kernel_launch(void* const* d_in, const int* in_sizes, int n_in,
                              void* d_out, int out_size, void* d_ws, size_t ws_size,
                              hipStream_t stream) {
    const long long N0 = in_sizes[0] / 3;
    const long long N1 = in_sizes[26] / 8;
    const long long N2 = in_sizes[27] / 8;
    const int P = 256;

    const float* feat = (const float*)d_in[0];
    const int* nbr0 = (const int*)d_in[23];
    const int* nbr1 = (const int*)d_in[24];
    const int* nbr2 = (const int*)d_in[25];
    const int* rb0  = (const int*)d_in[26];
    const int* rb1  = (const int*)d_in[27];

    double* part = (double*)d_ws;                        // 256*256 f64 = 512 KB
    float*  ab   = (float*)(part + (long long)P * 256);  // 12 * 256 f32
    float*  base = ab + 12 * 256;
    long long szBig = N0 * 32;
    if (N1 * 64 > szBig) szBig = N1 * 64;
    if (N2 * 96 > szBig) szBig = N2 * 96;
    long long szD = (N1 * 64 > N2 * 96) ? N1 * 64 : N2 * 96;
    float* D = base;            // x2 (N2x96), y1 (N1x64)
    float* A = D + szD;         // t0, d0, d1, u1, u0
    float* B = A + szBig;       // x0 skip (N0x32)
    float* C = B + N0 * 32;     // x1 (N1x64), y0 (N0x32)

#define STATS(CH, X, NN) bn_stats<CH><<<P, 256, 0, stream>>>(X, part, (int)(NN))
#define FIN(GBI, GBFULL, GOFF, SL, CH, NN)                                           \
    bn_fin<<<1, CH, 0, stream>>>(part, (const float*)d_in[GBI], GBFULL, GOFF,        \
                                 ab + (SL) * 256, CH, P, 1.0 / (double)(NN))
#define AB(SL) (ab + (SL) * 256)
#define WF(I) ((const float*)d_in[I])

    // ---- level 0 ----
    gconv<3, 32, 27, 8, 4, 3, false, false><<<(int)((N0 + 31) / 32), 256, 0, stream>>>(
        feat, nbr0, WF(1), 0, nullptr, A, (int)N0);                       // t0 -> A
    STATS(32, A, N0); FIN(2, 32, 0, 0, 32, N0);                           // bn1_0
    gconv2<32, 32, 128, 27, 256, 32, false><<<(int)((N0 + 127) / 128), 256, 0, stream>>>(
        A, nbr0, WF(3), 0, AB(0), B, (int)N0);                            // x0 -> B
    STATS(32, B, N0); FIN(4, 32, 0, 1, 32, N0);                           // bnd_0
    gconv2<32, 64, 64, 8, 256, 32, false><<<(int)((N1 + 63) / 64), 256, 0, stream>>>(
        B, rb0, WF(5), 0, AB(1), A, (int)N1);                             // d0 -> A

    // ---- level 1 ----
    STATS(64, A, N1); FIN(6, 64, 0, 2, 64, N1);                           // bn1_1
    gconv2<64, 64, 64, 27, 256, 64, false><<<(int)((N1 + 63) / 64), 256, 0, stream>>>(
        A, nbr1, WF(7), 0, AB(2), C, (int)N1);                            // x1 -> C
    STATS(64, C, N1); FIN(8, 64, 0, 3, 64, N1);                           // bnd_1
    gconv<64, 96, 8, 2, 4, 64, true, false><<<(int)((N2 + 7) / 8), 192, 0, stream>>>(
        C, rb1, WF(9), 0, AB(3), A, (int)N2);                             // d1 -> A

    // ---- level 2 ----
    STATS(96, A, N2); FIN(10, 96, 0, 4, 96, N2);                          // bn1_2
    gconv2<96, 96, 32, 27, 192, 96, false><<<(int)((N2 + 31) / 32), 192, 0, stream>>>(
        A, nbr2, WF(11), 0, AB(4), D, (int)N2);                           // x2 -> D
    STATS(96, D, N2); FIN(12, 96, 0, 5, 96, N2);                          // bnu_1

    // ---- up to level 1 (concat channel-separable) ----
    upconv<96, 64, 4><<<(int)((N2 + 3) / 4), 256, 0, stream>>>(
        D, rb1, WF(13), AB(5), A, (int)N2);                               // u1 -> A
    STATS(64, C, N1); FIN(14, 128, 0, 6, 64, N1);                         // bn2_1 [x1]
    STATS(64, A, N1); FIN(14, 128, 64, 7, 64, N1);                        // bn2_1 [u1]
    gconv2<64, 64, 64, 27, 256, 128, false><<<(int)((N1 + 63) / 64), 256, 0, stream>>>(
        C, nbr1, WF(15), 0, AB(6), D, (int)N1);                           // y1 p1 -> D
    gconv2<64, 64, 64, 27, 256, 128, true><<<(int)((N1 + 63) / 64), 256, 0, stream>>>(
        A, nbr1, WF(15), 64, AB(7), D, (int)N1);                          // y1 += p2
    STATS(64, D, N1); FIN(16, 64, 0, 8, 64, N1);                          // bnu_0

    // ---- up to level 0 ----
    upconv<64, 32, 8><<<(int)((N1 + 7) / 8), 256, 0, stream>>>(
        D, rb0, WF(17), AB(8), A, (int)N1);                               // u0 -> A
    STATS(32, B, N0); FIN(18, 64, 0, 9, 32, N0);                          // bn2_0 [x0]
    STATS(32, A, N0); FIN(18, 64, 32, 10, 32, N0);                        // bn2_0 [u0]
    gconv2<32, 32, 128, 27, 256, 64, false><<<(int)((N0 + 127) / 128), 256, 0, stream>>>(
        B, nbr0, WF(19), 0, AB(9), C, (int)N0);                           // y0 p1 -> C
    gconv2<32, 32, 128, 27, 256, 64, true><<<(int)((N0 + 127) / 128), 256, 0, stream>>>(
        A, nbr0, WF(19), 32, AB(10), C, (int)N0);                         // y0 += p2
    STATS(32, C, N0); FIN(20, 32, 0, 11, 32, N0);                         // bnf

    final_k<<<(int)((N0 + 255) / 256), 256, 0, stream>>>(
        C, AB(11), WF(21), WF(22), (float*)d_out, (int)N0);

#undef STATS
#undef FIN
#undef AB
#undef WF
}

// Round 12
// 2921.618 us; speedup vs baseline: 1.8127x; 1.1429x over previous
//
#include <hip/hip_runtime.h>
#include <hip/hip_bf16.h>

// ---------------------------------------------------------------------------
// Sparse 3-level U-Net, all-f32, f64 BN stats. Round 12: software-pipelined
// gconv2 (register prefetch of k+1 gather/weights during compute of k),
// register-blocked upconv2, parallel bn_fin, float4 final_k.
// Baseline R11: 3339 us (gconv2 ~300us, VALUBusy 49% -> barrier/gather bound).
// ---------------------------------------------------------------------------

// ---------- old-style gather conv (kept for t0 CIN=3 and d1 64->96) --------
template<int CIN, int COUT, int K, int TR, int ACC, int WROW, bool FUSEBN, bool ACCUM>
__global__ void gconv(const float* __restrict__ feat, const int* __restrict__ nbr,
                      const float* __restrict__ W, int cioff,
                      const float* __restrict__ ab, float* __restrict__ out, int N) {
    constexpr int T  = COUT * TR;
    constexpr int RB = TR * ACC;
    __shared__ float sW[CIN * COUT];
    __shared__ float sF[RB * CIN];
    __shared__ int   sIdx[RB];
    __shared__ float sA[FUSEBN ? CIN : 1];
    __shared__ float sB[FUSEBN ? CIN : 1];
    const int tid = threadIdx.x;
    const int c   = tid % COUT;
    const int r0  = tid / COUT;
    const long long row0 = (long long)blockIdx.x * RB;
    if (FUSEBN && tid < CIN) { sA[tid] = ab[tid]; sB[tid] = ab[CIN + tid]; }
    float acc[ACC];
#pragma unroll
    for (int a = 0; a < ACC; a++) acc[a] = 0.f;

    for (int k = 0; k < K; k++) {
        __syncthreads();
        if (tid < RB) {
            long long r = row0 + tid;
            sIdx[tid] = (r < N) ? nbr[r * K + k] : -1;
        }
        for (int e = tid; e < CIN * COUT; e += T) {
            int ci = e / COUT, cc = e - ci * COUT;
            sW[e] = W[((long long)k * WROW + ci + cioff) * COUT + cc];
        }
        __syncthreads();
        for (int e = tid; e < RB * CIN; e += T) {
            int r = e / CIN, ci = e - r * CIN;
            long long idx = sIdx[r];
            float v = 0.f;
            if (idx >= 0) {
                v = feat[idx * CIN + ci];
                if (FUSEBN) { v = v * sA[ci] + sB[ci]; v = v > 0.f ? v : 0.f; }
            }
            sF[e] = v;
        }
        __syncthreads();
#pragma unroll 4
        for (int ci = 0; ci < CIN; ci++) {
            float w = sW[ci * COUT + c];
#pragma unroll
            for (int a = 0; a < ACC; a++)
                acc[a] += sF[(r0 + a * TR) * CIN + ci] * w;
        }
    }
#pragma unroll
    for (int a = 0; a < ACC; a++) {
        long long r = row0 + r0 + a * TR;
        if (r < N) {
            float* p = &out[r * COUT + c];
            *p = ACCUM ? (*p + acc[a]) : acc[a];
        }
    }
}

// ---------- software-pipelined 2D-register-blocked gather conv -------------
// 4x4 tile/thread; k+1's nbr idx + feature float4s + weight float4s are
// prefetched into registers during compute of k (global latency hidden).
template<int CIN, int COUT, int BR, int K, int TPB, int WROW, bool ACCUM>
__global__ __launch_bounds__(TPB) void gconv2(
    const float* __restrict__ feat, const int* __restrict__ nbr,
    const float* __restrict__ W, int cioff,
    const float* __restrict__ ab, float* __restrict__ out, int N) {
    constexpr int CG  = COUT / 4;
    constexpr int RG  = BR / 4;
    static_assert(CG * RG == TPB, "tile/thread mismatch");
    constexpr int TPR = TPB / BR;
    constexpr int CPT = CIN / TPR;
    static_assert(TPR * BR == TPB && CPT * TPR == CIN && CPT % 4 == 0, "staging");
    constexpr int FCH = CPT / 4;
    constexpr int WCH = (CIN * COUT) / (TPB * 4);
    static_assert(WCH * TPB * 4 == CIN * COUT, "weight staging");
    constexpr int SFS = BR + 4;
    __shared__ float sW[CIN * COUT];
    __shared__ float sF[CIN * SFS];
    const int tid  = threadIdx.x;
    const int cg   = tid % CG;
    const int rg   = tid / CG;
    const int sr   = tid % BR;
    const int scio = (tid / BR) * CPT;
    const long long row0 = (long long)blockIdx.x * BR;
    const long long srow = row0 + sr;

    float ba[CPT], bb[CPT];
#pragma unroll
    for (int j = 0; j < CPT; j++) { ba[j] = ab[scio + j]; bb[j] = ab[CIN + scio + j]; }

    float acc[4][4];
#pragma unroll
    for (int i = 0; i < 4; i++)
#pragma unroll
        for (int l = 0; l < 4; l++) acc[i][l] = 0.f;

    float4 wreg[WCH], freg[FCH];
    int pidx;
    // ---- prefetch k = 0 ----
    {
        const float* wp = W + (long long)(0 * WROW + cioff) * COUT;
#pragma unroll
        for (int w = 0; w < WCH; w++)
            wreg[w] = *reinterpret_cast<const float4*>(wp + (tid + w * TPB) * 4);
        pidx = (srow < N) ? nbr[srow * K + 0] : -1;
        if (pidx >= 0) {
            const float* fr = feat + (long long)pidx * CIN + scio;
#pragma unroll
            for (int j = 0; j < FCH; j++)
                freg[j] = *reinterpret_cast<const float4*>(fr + 4 * j);
        }
    }

    for (int k = 0; k < K; k++) {
        __syncthreads();   // prior-iteration LDS reads done
        // commit staged registers to LDS
#pragma unroll
        for (int w = 0; w < WCH; w++)
            *reinterpret_cast<float4*>(sW + (tid + w * TPB) * 4) = wreg[w];
        if (pidx >= 0) {
#pragma unroll
            for (int j = 0; j < FCH; j++) {
                float4 v = freg[j];
                float t0 = v.x * ba[4 * j]     + bb[4 * j];
                float t1 = v.y * ba[4 * j + 1] + bb[4 * j + 1];
                float t2 = v.z * ba[4 * j + 2] + bb[4 * j + 2];
                float t3 = v.w * ba[4 * j + 3] + bb[4 * j + 3];
                sF[(scio + 4 * j)     * SFS + sr] = t0 > 0.f ? t0 : 0.f;
                sF[(scio + 4 * j + 1) * SFS + sr] = t1 > 0.f ? t1 : 0.f;
                sF[(scio + 4 * j + 2) * SFS + sr] = t2 > 0.f ? t2 : 0.f;
                sF[(scio + 4 * j + 3) * SFS + sr] = t3 > 0.f ? t3 : 0.f;
            }
        } else {
#pragma unroll
            for (int j = 0; j < CPT; j++) sF[(scio + j) * SFS + sr] = 0.f;
        }
        __syncthreads();
        // prefetch k+1 (overlaps with compute below)
        if (k + 1 < K) {
            const float* wp = W + (long long)((k + 1) * WROW + cioff) * COUT;
#pragma unroll
            for (int w = 0; w < WCH; w++)
                wreg[w] = *reinterpret_cast<const float4*>(wp + (tid + w * TPB) * 4);
            pidx = (srow < N) ? nbr[srow * K + (k + 1)] : -1;
            if (pidx >= 0) {
                const float* fr = feat + (long long)pidx * CIN + scio;
#pragma unroll
                for (int j = 0; j < FCH; j++)
                    freg[j] = *reinterpret_cast<const float4*>(fr + 4 * j);
            }
        }
        // compute: per 4-ci chunk, 8 x b128 LDS + 64 FMA
#pragma unroll 4
        for (int ci = 0; ci < CIN; ci += 4) {
#pragma unroll
            for (int j = 0; j < 4; j++) {
                float4 wv = *reinterpret_cast<const float4*>(sW + (ci + j) * COUT + 4 * cg);
                float4 fv = *reinterpret_cast<const float4*>(sF + (ci + j) * SFS + 4 * rg);
                const float wq[4] = {wv.x, wv.y, wv.z, wv.w};
                const float fq[4] = {fv.x, fv.y, fv.z, fv.w};
#pragma unroll
                for (int i = 0; i < 4; i++)
#pragma unroll
                    for (int l = 0; l < 4; l++)
                        acc[i][l] = fmaf(fq[i], wq[l], acc[i][l]);
            }
        }
    }
#pragma unroll
    for (int i = 0; i < 4; i++) {
        long long r = row0 + 4 * rg + i;
        if (r < N) {
            float* p = out + r * COUT + 4 * cg;
            if (ACCUM) {
                float4 o = *reinterpret_cast<float4*>(p);
                o.x += acc[i][0]; o.y += acc[i][1]; o.z += acc[i][2]; o.w += acc[i][3];
                *reinterpret_cast<float4*>(p) = o;
            } else {
                *reinterpret_cast<float4*>(p) =
                    make_float4(acc[i][0], acc[i][1], acc[i][2], acc[i][3]);
            }
        }
    }
}

// ---------- register-blocked transposed (up) conv --------------------------
// Features staged once (BN fused, transposed). Per octant k: weights+indices
// prefetched in registers, fresh 4x4 tile, permutation scatter stores.
template<int CIN, int COUT, int BR, int TPB>
__global__ __launch_bounds__(TPB) void upconv2(
    const float* __restrict__ featc, const int* __restrict__ rb,
    const float* __restrict__ W, const float* __restrict__ ab,
    float* __restrict__ out, int N) {
    constexpr int K   = 8;
    constexpr int CG  = COUT / 4;
    constexpr int RG  = BR / 4;
    static_assert(CG * RG == TPB, "tile/thread mismatch");
    constexpr int TPR = TPB / BR;
    constexpr int CPT = CIN / TPR;
    static_assert(TPR * BR == TPB && CPT * TPR == CIN && CPT % 4 == 0, "staging");
    constexpr int WCH = (CIN * COUT) / (TPB * 4);
    static_assert(WCH * TPB * 4 == CIN * COUT, "weight staging");
    constexpr int SFS = BR + 4;
    __shared__ float sW[CIN * COUT];
    __shared__ float sF[CIN * SFS];
    const int tid  = threadIdx.x;
    const int cg   = tid % CG;
    const int rg   = tid / CG;
    const int sr   = tid % BR;
    const int scio = (tid / BR) * CPT;
    const long long row0 = (long long)blockIdx.x * BR;
    const long long srow = row0 + sr;

    // stage features once: BN+relu, transposed
    if (srow < N) {
        const float* fr = featc + srow * CIN + scio;
#pragma unroll
        for (int j = 0; j < CPT; j += 4) {
            float4 v = *reinterpret_cast<const float4*>(fr + j);
            float t0 = v.x * ab[scio + j]     + ab[CIN + scio + j];
            float t1 = v.y * ab[scio + j + 1] + ab[CIN + scio + j + 1];
            float t2 = v.z * ab[scio + j + 2] + ab[CIN + scio + j + 2];
            float t3 = v.w * ab[scio + j + 3] + ab[CIN + scio + j + 3];
            sF[(scio + j)     * SFS + sr] = t0 > 0.f ? t0 : 0.f;
            sF[(scio + j + 1) * SFS + sr] = t1 > 0.f ? t1 : 0.f;
            sF[(scio + j + 2) * SFS + sr] = t2 > 0.f ? t2 : 0.f;
            sF[(scio + j + 3) * SFS + sr] = t3 > 0.f ? t3 : 0.f;
        }
    } else {
#pragma unroll
        for (int j = 0; j < CPT; j++) sF[(scio + j) * SFS + sr] = 0.f;
    }

    float4 wreg[WCH];
    int pidx[4];
    {
#pragma unroll
        for (int w = 0; w < WCH; w++)
            wreg[w] = *reinterpret_cast<const float4*>(W + (tid + w * TPB) * 4);
#pragma unroll
        for (int i = 0; i < 4; i++) {
            long long r = row0 + 4 * rg + i;
            pidx[i] = (r < N) ? rb[r * K + 0] : -1;
        }
    }

    for (int k = 0; k < K; k++) {
        __syncthreads();   // prior compute done (and sF staging visible at k=0)
#pragma unroll
        for (int w = 0; w < WCH; w++)
            *reinterpret_cast<float4*>(sW + (tid + w * TPB) * 4) = wreg[w];
        __syncthreads();
        int sidx[4];
#pragma unroll
        for (int i = 0; i < 4; i++) sidx[i] = pidx[i];
        if (k + 1 < K) {
            const float* wp = W + (long long)(k + 1) * CIN * COUT;
#pragma unroll
            for (int w = 0; w < WCH; w++)
                wreg[w] = *reinterpret_cast<const float4*>(wp + (tid + w * TPB) * 4);
#pragma unroll
            for (int i = 0; i < 4; i++) {
                long long r = row0 + 4 * rg + i;
                pidx[i] = (r < N) ? rb[r * K + (k + 1)] : -1;
            }
        }
        float acc[4][4];
#pragma unroll
        for (int i = 0; i < 4; i++)
#pragma unroll
            for (int l = 0; l < 4; l++) acc[i][l] = 0.f;
#pragma unroll 4
        for (int ci = 0; ci < CIN; ci += 4) {
#pragma unroll
            for (int j = 0; j < 4; j++) {
                float4 wv = *reinterpret_cast<const float4*>(sW + (ci + j) * COUT + 4 * cg);
                float4 fv = *reinterpret_cast<const float4*>(sF + (ci + j) * SFS + 4 * rg);
                const float wq[4] = {wv.x, wv.y, wv.z, wv.w};
                const float fq[4] = {fv.x, fv.y, fv.z, fv.w};
#pragma unroll
                for (int i = 0; i < 4; i++)
#pragma unroll
                    for (int l = 0; l < 4; l++)
                        acc[i][l] = fmaf(fq[i], wq[l], acc[i][l]);
            }
        }
#pragma unroll
        for (int i = 0; i < 4; i++) {
            if (sidx[i] >= 0) {
                *reinterpret_cast<float4*>(out + (long long)sidx[i] * COUT + 4 * cg) =
                    make_float4(acc[i][0], acc[i][1], acc[i][2], acc[i][3]);
            }
        }
    }
}

// ---------- BN stats (two-pass, deterministic, f64) ------------------------
template<int C>
__global__ void bn_stats(const float* __restrict__ x, double* __restrict__ part, int N) {
    constexpr int RPB = 256 / C;
    __shared__ double ls[256], lq[256];
    const int tid = threadIdx.x;
    double s = 0.0, q = 0.0;
    if (tid < RPB * C) {
        const int c  = tid % C;
        const int rr = tid / C;
        for (long long r = (long long)blockIdx.x * RPB + rr; r < N;
             r += (long long)gridDim.x * RPB) {
            double v = (double)x[r * C + c];
            s += v; q += v * v;
        }
    }
    ls[tid] = s; lq[tid] = q;
    __syncthreads();
    if (tid < C) {
        for (int j = 1; j < RPB; j++) { s += ls[j * C + tid]; q += lq[j * C + tid]; }
        part[blockIdx.x * 256 + tid]       = s;
        part[blockIdx.x * 256 + 128 + tid] = q;
    }
}

// parallel finalize: 256 threads, G=256/C groups split the P partials.
__global__ void bn_fin(const double* __restrict__ part, const float* __restrict__ gb,
                       int gbfull, int goff, float* __restrict__ ab,
                       int C, int P, double invN) {
    __shared__ double ss[256], sq[256];
    const int tid = threadIdx.x;
    const int c   = tid % C;
    const int g   = tid / C;
    const int G   = 256 / C;
    double s = 0.0, q = 0.0;
    if (g < G) {
        for (int p = g; p < P; p += G) {
            s += part[p * 256 + c];
            q += part[p * 256 + 128 + c];
        }
    }
    ss[tid] = s; sq[tid] = q;
    __syncthreads();
    if (tid < C) {
        for (int j = 1; j < G; j++) { s += ss[j * C + c]; q += sq[j * C + c]; }
        double mu  = s * invN;
        double var = q * invN - mu * mu;
        double a   = (double)gb[goff + c] / sqrt(var + 1e-4);
        ab[c]     = (float)a;
        ab[C + c] = (float)((double)gb[gbfull + goff + c] - mu * a);
    }
}

// ---------- final linear (bnf fused), float4 loads -------------------------
__global__ void final_k(const float* __restrict__ x, const float* __restrict__ ab,
                        const float* __restrict__ lw, const float* __restrict__ lb,
                        float* __restrict__ out, int N) {
    long long r = (long long)blockIdx.x * blockDim.x + threadIdx.x;
    if (r >= N) return;
    float a0 = lb[0], a1 = lb[1];
    const float4* xp = reinterpret_cast<const float4*>(x + r * 32);
#pragma unroll
    for (int j = 0; j < 8; j++) {
        float4 v = xp[j];
        const float vv[4] = {v.x, v.y, v.z, v.w};
#pragma unroll
        for (int t = 0; t < 4; t++) {
            int ci = 4 * j + t;
            float u = vv[t] * ab[ci] + ab[32 + ci];
            u = u > 0.f ? u : 0.f;
            a0 += u * lw[ci * 2];
            a1 += u * lw[ci * 2 + 1];
        }
    }
    out[2 * r]     = a0;
    out[2 * r + 1] = a1;
}

extern "C" void kernel_launch(void* const* d_in, const int* in_sizes, int n_in,
                              void* d_out, int out_size, void* d_ws, size_t ws_size,
                              hipStream_t stream) {
    const long long N0 = in_sizes[0] / 3;
    const long long N1 = in_sizes[26] / 8;
    const long long N2 = in_sizes[27] / 8;
    const int P = 256;

    const float* feat = (const float*)d_in[0];
    const int* nbr0 = (const int*)d_in[23];
    const int* nbr1 = (const int*)d_in[24];
    const int* nbr2 = (const int*)d_in[25];
    const int* rb0  = (const int*)d_in[26];
    const int* rb1  = (const int*)d_in[27];

    double* part = (double*)d_ws;                        // 256*256 f64 = 512 KB
    float*  ab   = (float*)(part + (long long)P * 256);  // 12 * 256 f32
    float*  base = ab + 12 * 256;
    long long szBig = N0 * 32;
    if (N1 * 64 > szBig) szBig = N1 * 64;
    if (N2 * 96 > szBig) szBig = N2 * 96;
    long long szD = (N1 * 64 > N2 * 96) ? N1 * 64 : N2 * 96;
    float* D = base;            // x2 (N2x96), y1 (N1x64)
    float* A = D + szD;         // t0, d0, d1, u1, u0
    float* B = A + szBig;       // x0 skip (N0x32)
    float* C = B + N0 * 32;     // x1 (N1x64), y0 (N0x32)

#define STATS(CH, X, NN) bn_stats<CH><<<P, 256, 0, stream>>>(X, part, (int)(NN))
#define FIN(GBI, GBFULL, GOFF, SL, CH, NN)                                           \
    bn_fin<<<1, 256, 0, stream>>>(part, (const float*)d_in[GBI], GBFULL, GOFF,       \
                                  ab + (SL) * 256, CH, P, 1.0 / (double)(NN))
#define AB(SL) (ab + (SL) * 256)
#define WF(I) ((const float*)d_in[I])

    // ---- level 0 ----
    gconv<3, 32, 27, 8, 4, 3, false, false><<<(int)((N0 + 31) / 32), 256, 0, stream>>>(
        feat, nbr0, WF(1), 0, nullptr, A, (int)N0);                       // t0 -> A
    STATS(32, A, N0); FIN(2, 32, 0, 0, 32, N0);                           // bn1_0
    gconv2<32, 32, 128, 27, 256, 32, false><<<(int)((N0 + 127) / 128), 256, 0, stream>>>(
        A, nbr0, WF(3), 0, AB(0), B, (int)N0);                            // x0 -> B
    STATS(32, B, N0); FIN(4, 32, 0, 1, 32, N0);                           // bnd_0
    gconv2<32, 64, 64, 8, 256, 32, false><<<(int)((N1 + 63) / 64), 256, 0, stream>>>(
        B, rb0, WF(5), 0, AB(1), A, (int)N1);                             // d0 -> A

    // ---- level 1 ----
    STATS(64, A, N1); FIN(6, 64, 0, 2, 64, N1);                           // bn1_1
    gconv2<64, 64, 64, 27, 256, 64, false><<<(int)((N1 + 63) / 64), 256, 0, stream>>>(
        A, nbr1, WF(7), 0, AB(2), C, (int)N1);                            // x1 -> C
    STATS(64, C, N1); FIN(8, 64, 0, 3, 64, N1);                           // bnd_1
    gconv<64, 96, 8, 2, 4, 64, true, false><<<(int)((N2 + 7) / 8), 192, 0, stream>>>(
        C, rb1, WF(9), 0, AB(3), A, (int)N2);                             // d1 -> A

    // ---- level 2 ----
    STATS(96, A, N2); FIN(10, 96, 0, 4, 96, N2);                          // bn1_2
    gconv2<96, 96, 32, 27, 192, 96, false><<<(int)((N2 + 31) / 32), 192, 0, stream>>>(
        A, nbr2, WF(11), 0, AB(4), D, (int)N2);                           // x2 -> D
    STATS(96, D, N2); FIN(12, 96, 0, 5, 96, N2);                          // bnu_1

    // ---- up to level 1 (concat channel-separable) ----
    upconv2<96, 64, 64, 256><<<(int)((N2 + 63) / 64), 256, 0, stream>>>(
        D, rb1, WF(13), AB(5), A, (int)N2);                               // u1 -> A
    STATS(64, C, N1); FIN(14, 128, 0, 6, 64, N1);                         // bn2_1 [x1]
    STATS(64, A, N1); FIN(14, 128, 64, 7, 64, N1);                        // bn2_1 [u1]
    gconv2<64, 64, 64, 27, 256, 128, false><<<(int)((N1 + 63) / 64), 256, 0, stream>>>(
        C, nbr1, WF(15), 0, AB(6), D, (int)N1);                           // y1 p1 -> D
    gconv2<64, 64, 64, 27, 256, 128, true><<<(int)((N1 + 63) / 64), 256, 0, stream>>>(
        A, nbr1, WF(15), 64, AB(7), D, (int)N1);                          // y1 += p2
    STATS(64, D, N1); FIN(16, 64, 0, 8, 64, N1);                          // bnu_0

    // ---- up to level 0 ----
    upconv2<64, 32, 128, 256><<<(int)((N1 + 127) / 128), 256, 0, stream>>>(
        D, rb0, WF(17), AB(8), A, (int)N1);                               // u0 -> A
    STATS(32, B, N0); FIN(18, 64, 0, 9, 32, N0);                          // bn2_0 [x0]
    STATS(32, A, N0); FIN(18, 64, 32, 10, 32, N0);                        // bn2_0 [u0]
    gconv2<32, 32, 128, 27, 256, 64, false><<<(int)((N0 + 127) / 128), 256, 0, stream>>>(
        B, nbr0, WF(19), 0, AB(9), C, (int)N0);                           // y0 p1 -> C
    gconv2<32, 32, 128, 27, 256, 64, true><<<(int)((N0 + 127) / 128), 256, 0, stream>>>(
        A, nbr0, WF(19), 32, AB(10), C, (int)N0);                         // y0 += p2
    STATS(32, C, N0); FIN(20, 32, 0, 11, 32, N0);                         // bnf

    final_k<<<(int)((N0 + 255) / 256), 256, 0, stream>>>(
        C, AB(11), WF(21), WF(22), (float*)d_out, (int)N0);

#undef STATS
#undef FIN
#undef AB
#undef WF
}

// Round 13
// 2603.178 us; speedup vs baseline: 2.0345x; 1.1223x over previous
//
#include <hip/hip_runtime.h>
#include <hip/hip_bf16.h>

// ---------------------------------------------------------------------------
// Sparse 3-level U-Net, all-f32, f64 BN stats. Round 13: fix R12's register
// spill (WRITE_SIZE 418MB = scratch traffic): feature-only register prefetch
// (weight prefetch dropped — weights are L2-hot), __launch_bounds__ min-waves
// matched to LDS residency, dedicated flat kernel for the CIN=3 input conv.
// Baseline R12: 2921 us.
// ---------------------------------------------------------------------------

// ---------- flat input conv (CIN=3): one thread per row, no k-loop barriers
__global__ __launch_bounds__(256) void conv_in(
    const float* __restrict__ feat, const int* __restrict__ nbr,
    const float* __restrict__ W, float* __restrict__ out, int N) {
    __shared__ float sW[27 * 3 * 32];
    const int tid = threadIdx.x;
    for (int e = tid; e < 27 * 96; e += 256) sW[e] = W[e];
    __syncthreads();
    long long r = (long long)blockIdx.x * 256 + tid;
    if (r >= N) return;
    float acc[32];
#pragma unroll
    for (int c = 0; c < 32; c++) acc[c] = 0.f;
    for (int k = 0; k < 27; k++) {
        int idx = nbr[r * 27 + k];
        if (idx >= 0) {
            float f0 = feat[(long long)idx * 3];
            float f1 = feat[(long long)idx * 3 + 1];
            float f2 = feat[(long long)idx * 3 + 2];
            const float* w = sW + k * 96;   // uniform address -> LDS broadcast
#pragma unroll
            for (int c = 0; c < 32; c++)
                acc[c] += f0 * w[c] + f1 * w[32 + c] + f2 * w[64 + c];
        }
    }
    float4* op = reinterpret_cast<float4*>(out + r * 32);
#pragma unroll
    for (int j = 0; j < 8; j++)
        op[j] = make_float4(acc[4 * j], acc[4 * j + 1], acc[4 * j + 2], acc[4 * j + 3]);
}

// ---------- old-style gather conv (kept for d1 64->96) ---------------------
template<int CIN, int COUT, int K, int TR, int ACC, int WROW, bool FUSEBN, bool ACCUM>
__global__ void gconv(const float* __restrict__ feat, const int* __restrict__ nbr,
                      const float* __restrict__ W, int cioff,
                      const float* __restrict__ ab, float* __restrict__ out, int N) {
    constexpr int T  = COUT * TR;
    constexpr int RB = TR * ACC;
    __shared__ float sW[CIN * COUT];
    __shared__ float sF[RB * CIN];
    __shared__ int   sIdx[RB];
    __shared__ float sA[FUSEBN ? CIN : 1];
    __shared__ float sB[FUSEBN ? CIN : 1];
    const int tid = threadIdx.x;
    const int c   = tid % COUT;
    const int r0  = tid / COUT;
    const long long row0 = (long long)blockIdx.x * RB;
    if (FUSEBN && tid < CIN) { sA[tid] = ab[tid]; sB[tid] = ab[CIN + tid]; }
    float acc[ACC];
#pragma unroll
    for (int a = 0; a < ACC; a++) acc[a] = 0.f;

    for (int k = 0; k < K; k++) {
        __syncthreads();
        if (tid < RB) {
            long long r = row0 + tid;
            sIdx[tid] = (r < N) ? nbr[r * K + k] : -1;
        }
        for (int e = tid; e < CIN * COUT; e += T) {
            int ci = e / COUT, cc = e - ci * COUT;
            sW[e] = W[((long long)k * WROW + ci + cioff) * COUT + cc];
        }
        __syncthreads();
        for (int e = tid; e < RB * CIN; e += T) {
            int r = e / CIN, ci = e - r * CIN;
            long long idx = sIdx[r];
            float v = 0.f;
            if (idx >= 0) {
                v = feat[idx * CIN + ci];
                if (FUSEBN) { v = v * sA[ci] + sB[ci]; v = v > 0.f ? v : 0.f; }
            }
            sF[e] = v;
        }
        __syncthreads();
#pragma unroll 4
        for (int ci = 0; ci < CIN; ci++) {
            float w = sW[ci * COUT + c];
#pragma unroll
            for (int a = 0; a < ACC; a++)
                acc[a] += sF[(r0 + a * TR) * CIN + ci] * w;
        }
    }
#pragma unroll
    for (int a = 0; a < ACC; a++) {
        long long r = row0 + r0 + a * TR;
        if (r < N) {
            float* p = &out[r * COUT + c];
            *p = ACCUM ? (*p + acc[a]) : acc[a];
        }
    }
}

// ---------- pipelined 2D-register-blocked gather conv ----------------------
// 4x4 tile/thread. ONLY features+index prefetched in registers (weights are
// L2-hot, staged global->LDS directly). MINW = min waves/SIMD for allocator.
template<int CIN, int COUT, int BR, int K, int TPB, int WROW, int MINW, bool ACCUM>
__global__ __launch_bounds__(TPB, MINW) void gconv2(
    const float* __restrict__ feat, const int* __restrict__ nbr,
    const float* __restrict__ W, int cioff,
    const float* __restrict__ ab, float* __restrict__ out, int N) {
    constexpr int CG  = COUT / 4;
    constexpr int RG  = BR / 4;
    static_assert(CG * RG == TPB, "tile/thread mismatch");
    constexpr int TPR = TPB / BR;
    constexpr int CPT = CIN / TPR;
    static_assert(TPR * BR == TPB && CPT * TPR == CIN && CPT % 4 == 0, "staging");
    constexpr int FCH = CPT / 4;
    constexpr int SFS = BR + 4;
    __shared__ float sW[CIN * COUT];
    __shared__ float sF[CIN * SFS];
    const int tid  = threadIdx.x;
    const int cg   = tid % CG;
    const int rg   = tid / CG;
    const int sr   = tid % BR;
    const int scio = (tid / BR) * CPT;
    const long long row0 = (long long)blockIdx.x * BR;
    const long long srow = row0 + sr;

    float ba[CPT], bb[CPT];
#pragma unroll
    for (int j = 0; j < CPT; j++) { ba[j] = ab[scio + j]; bb[j] = ab[CIN + scio + j]; }

    float acc[4][4];
#pragma unroll
    for (int i = 0; i < 4; i++)
#pragma unroll
        for (int l = 0; l < 4; l++) acc[i][l] = 0.f;

    float4 freg[FCH];
    int pidx = (srow < N) ? nbr[srow * K + 0] : -1;
    if (pidx >= 0) {
        const float* fr = feat + (long long)pidx * CIN + scio;
#pragma unroll
        for (int j = 0; j < FCH; j++)
            freg[j] = *reinterpret_cast<const float4*>(fr + 4 * j);
    }

    for (int k = 0; k < K; k++) {
        __syncthreads();   // prior-iteration LDS reads done
        // weights: global(L2-hot) -> LDS
        for (int e = tid * 4; e < CIN * COUT; e += TPB * 4) {
            int ci = e / COUT, cc = e - ci * COUT;
            *reinterpret_cast<float4*>(sW + e) = *reinterpret_cast<const float4*>(
                W + ((long long)k * WROW + ci + cioff) * COUT + cc);
        }
        // commit prefetched features (BN+relu) to LDS, transposed
        if (pidx >= 0) {
#pragma unroll
            for (int j = 0; j < FCH; j++) {
                float4 v = freg[j];
                float t0 = v.x * ba[4 * j]     + bb[4 * j];
                float t1 = v.y * ba[4 * j + 1] + bb[4 * j + 1];
                float t2 = v.z * ba[4 * j + 2] + bb[4 * j + 2];
                float t3 = v.w * ba[4 * j + 3] + bb[4 * j + 3];
                sF[(scio + 4 * j)     * SFS + sr] = t0 > 0.f ? t0 : 0.f;
                sF[(scio + 4 * j + 1) * SFS + sr] = t1 > 0.f ? t1 : 0.f;
                sF[(scio + 4 * j + 2) * SFS + sr] = t2 > 0.f ? t2 : 0.f;
                sF[(scio + 4 * j + 3) * SFS + sr] = t3 > 0.f ? t3 : 0.f;
            }
        } else {
#pragma unroll
            for (int j = 0; j < CPT; j++) sF[(scio + j) * SFS + sr] = 0.f;
        }
        __syncthreads();
        // prefetch k+1 features (overlaps compute)
        if (k + 1 < K) {
            pidx = (srow < N) ? nbr[srow * K + (k + 1)] : -1;
            if (pidx >= 0) {
                const float* fr = feat + (long long)pidx * CIN + scio;
#pragma unroll
                for (int j = 0; j < FCH; j++)
                    freg[j] = *reinterpret_cast<const float4*>(fr + 4 * j);
            }
        }
        // compute: per 4-ci chunk, 8 x b128 LDS + 64 FMA
#pragma unroll 4
        for (int ci = 0; ci < CIN; ci += 4) {
#pragma unroll
            for (int j = 0; j < 4; j++) {
                float4 wv = *reinterpret_cast<const float4*>(sW + (ci + j) * COUT + 4 * cg);
                float4 fv = *reinterpret_cast<const float4*>(sF + (ci + j) * SFS + 4 * rg);
                const float wq[4] = {wv.x, wv.y, wv.z, wv.w};
                const float fq[4] = {fv.x, fv.y, fv.z, fv.w};
#pragma unroll
                for (int i = 0; i < 4; i++)
#pragma unroll
                    for (int l = 0; l < 4; l++)
                        acc[i][l] = fmaf(fq[i], wq[l], acc[i][l]);
            }
        }
    }
#pragma unroll
    for (int i = 0; i < 4; i++) {
        long long r = row0 + 4 * rg + i;
        if (r < N) {
            float* p = out + r * COUT + 4 * cg;
            if (ACCUM) {
                float4 o = *reinterpret_cast<float4*>(p);
                o.x += acc[i][0]; o.y += acc[i][1]; o.z += acc[i][2]; o.w += acc[i][3];
                *reinterpret_cast<float4*>(p) = o;
            } else {
                *reinterpret_cast<float4*>(p) =
                    make_float4(acc[i][0], acc[i][1], acc[i][2], acc[i][3]);
            }
        }
    }
}

// ---------- register-blocked transposed (up) conv --------------------------
template<int CIN, int COUT, int BR, int TPB>
__global__ __launch_bounds__(TPB, 4) void upconv2(
    const float* __restrict__ featc, const int* __restrict__ rb,
    const float* __restrict__ W, const float* __restrict__ ab,
    float* __restrict__ out, int N) {
    constexpr int K   = 8;
    constexpr int CG  = COUT / 4;
    constexpr int RG  = BR / 4;
    static_assert(CG * RG == TPB, "tile/thread mismatch");
    constexpr int TPR = TPB / BR;
    constexpr int CPT = CIN / TPR;
    static_assert(TPR * BR == TPB && CPT * TPR == CIN && CPT % 4 == 0, "staging");
    constexpr int SFS = BR + 4;
    __shared__ float sW[CIN * COUT];
    __shared__ float sF[CIN * SFS];
    const int tid  = threadIdx.x;
    const int cg   = tid % CG;
    const int rg   = tid / CG;
    const int sr   = tid % BR;
    const int scio = (tid / BR) * CPT;
    const long long row0 = (long long)blockIdx.x * BR;
    const long long srow = row0 + sr;

    if (srow < N) {
        const float* fr = featc + srow * CIN + scio;
#pragma unroll
        for (int j = 0; j < CPT; j += 4) {
            float4 v = *reinterpret_cast<const float4*>(fr + j);
            float t0 = v.x * ab[scio + j]     + ab[CIN + scio + j];
            float t1 = v.y * ab[scio + j + 1] + ab[CIN + scio + j + 1];
            float t2 = v.z * ab[scio + j + 2] + ab[CIN + scio + j + 2];
            float t3 = v.w * ab[scio + j + 3] + ab[CIN + scio + j + 3];
            sF[(scio + j)     * SFS + sr] = t0 > 0.f ? t0 : 0.f;
            sF[(scio + j + 1) * SFS + sr] = t1 > 0.f ? t1 : 0.f;
            sF[(scio + j + 2) * SFS + sr] = t2 > 0.f ? t2 : 0.f;
            sF[(scio + j + 3) * SFS + sr] = t3 > 0.f ? t3 : 0.f;
        }
    } else {
#pragma unroll
        for (int j = 0; j < CPT; j++) sF[(scio + j) * SFS + sr] = 0.f;
    }

    int pidx[4];
#pragma unroll
    for (int i = 0; i < 4; i++) {
        long long r = row0 + 4 * rg + i;
        pidx[i] = (r < N) ? rb[r * K + 0] : -1;
    }

    for (int k = 0; k < K; k++) {
        __syncthreads();
        for (int e = tid * 4; e < CIN * COUT; e += TPB * 4)
            *reinterpret_cast<float4*>(sW + e) =
                *reinterpret_cast<const float4*>(W + (long long)k * CIN * COUT + e);
        __syncthreads();
        int sidx[4];
#pragma unroll
        for (int i = 0; i < 4; i++) sidx[i] = pidx[i];
        if (k + 1 < K) {
#pragma unroll
            for (int i = 0; i < 4; i++) {
                long long r = row0 + 4 * rg + i;
                pidx[i] = (r < N) ? rb[r * K + (k + 1)] : -1;
            }
        }
        float acc[4][4];
#pragma unroll
        for (int i = 0; i < 4; i++)
#pragma unroll
            for (int l = 0; l < 4; l++) acc[i][l] = 0.f;
#pragma unroll 4
        for (int ci = 0; ci < CIN; ci += 4) {
#pragma unroll
            for (int j = 0; j < 4; j++) {
                float4 wv = *reinterpret_cast<const float4*>(sW + (ci + j) * COUT + 4 * cg);
                float4 fv = *reinterpret_cast<const float4*>(sF + (ci + j) * SFS + 4 * rg);
                const float wq[4] = {wv.x, wv.y, wv.z, wv.w};
                const float fq[4] = {fv.x, fv.y, fv.z, fv.w};
#pragma unroll
                for (int i = 0; i < 4; i++)
#pragma unroll
                    for (int l = 0; l < 4; l++)
                        acc[i][l] = fmaf(fq[i], wq[l], acc[i][l]);
            }
        }
#pragma unroll
        for (int i = 0; i < 4; i++) {
            if (sidx[i] >= 0) {
                *reinterpret_cast<float4*>(out + (long long)sidx[i] * COUT + 4 * cg) =
                    make_float4(acc[i][0], acc[i][1], acc[i][2], acc[i][3]);
            }
        }
    }
}

// ---------- BN stats (two-pass, deterministic, f64) ------------------------
template<int C>
__global__ void bn_stats(const float* __restrict__ x, double* __restrict__ part, int N) {
    constexpr int RPB = 256 / C;
    __shared__ double ls[256], lq[256];
    const int tid = threadIdx.x;
    double s = 0.0, q = 0.0;
    if (tid < RPB * C) {
        const int c  = tid % C;
        const int rr = tid / C;
        for (long long r = (long long)blockIdx.x * RPB + rr; r < N;
             r += (long long)gridDim.x * RPB) {
            double v = (double)x[r * C + c];
            s += v; q += v * v;
        }
    }
    ls[tid] = s; lq[tid] = q;
    __syncthreads();
    if (tid < C) {
        for (int j = 1; j < RPB; j++) { s += ls[j * C + tid]; q += lq[j * C + tid]; }
        part[blockIdx.x * 256 + tid]       = s;
        part[blockIdx.x * 256 + 128 + tid] = q;
    }
}

__global__ void bn_fin(const double* __restrict__ part, const float* __restrict__ gb,
                       int gbfull, int goff, float* __restrict__ ab,
                       int C, int P, double invN) {
    __shared__ double ss[256], sq[256];
    const int tid = threadIdx.x;
    const int c   = tid % C;
    const int g   = tid / C;
    const int G   = 256 / C;
    double s = 0.0, q = 0.0;
    if (g < G) {
        for (int p = g; p < P; p += G) {
            s += part[p * 256 + c];
            q += part[p * 256 + 128 + c];
        }
    }
    ss[tid] = s; sq[tid] = q;
    __syncthreads();
    if (tid < C) {
        for (int j = 1; j < G; j++) { s += ss[j * C + c]; q += sq[j * C + c]; }
        double mu  = s * invN;
        double var = q * invN - mu * mu;
        double a   = (double)gb[goff + c] / sqrt(var + 1e-4);
        ab[c]     = (float)a;
        ab[C + c] = (float)((double)gb[gbfull + goff + c] - mu * a);
    }
}

// ---------- final linear (bnf fused), float4 loads -------------------------
__global__ void final_k(const float* __restrict__ x, const float* __restrict__ ab,
                        const float* __restrict__ lw, const float* __restrict__ lb,
                        float* __restrict__ out, int N) {
    long long r = (long long)blockIdx.x * blockDim.x + threadIdx.x;
    if (r >= N) return;
    float a0 = lb[0], a1 = lb[1];
    const float4* xp = reinterpret_cast<const float4*>(x + r * 32);
#pragma unroll
    for (int j = 0; j < 8; j++) {
        float4 v = xp[j];
        const float vv[4] = {v.x, v.y, v.z, v.w};
#pragma unroll
        for (int t = 0; t < 4; t++) {
            int ci = 4 * j + t;
            float u = vv[t] * ab[ci] + ab[32 + ci];
            u = u > 0.f ? u : 0.f;
            a0 += u * lw[ci * 2];
            a1 += u * lw[ci * 2 + 1];
        }
    }
    out[2 * r]     = a0;
    out[2 * r + 1] = a1;
}

extern "C" void kernel_launch(void* const* d_in, const int* in_sizes, int n_in,
                              void* d_out, int out_size, void* d_ws, size_t ws_size,
                              hipStream_t stream) {
    const long long N0 = in_sizes[0] / 3;
    const long long N1 = in_sizes[26] / 8;
    const long long N2 = in_sizes[27] / 8;
    const int P = 256;

    const float* feat = (const float*)d_in[0];
    const int* nbr0 = (const int*)d_in[23];
    const int* nbr1 = (const int*)d_in[24];
    const int* nbr2 = (const int*)d_in[25];
    const int* rb0  = (const int*)d_in[26];
    const int* rb1  = (const int*)d_in[27];

    double* part = (double*)d_ws;                        // 256*256 f64 = 512 KB
    float*  ab   = (float*)(part + (long long)P * 256);  // 12 * 256 f32
    float*  base = ab + 12 * 256;
    long long szBig = N0 * 32;
    if (N1 * 64 > szBig) szBig = N1 * 64;
    if (N2 * 96 > szBig) szBig = N2 * 96;
    long long szD = (N1 * 64 > N2 * 96) ? N1 * 64 : N2 * 96;
    float* D = base;            // x2 (N2x96), y1 (N1x64)
    float* A = D + szD;         // t0, d0, d1, u1, u0
    float* B = A + szBig;       // x0 skip (N0x32)
    float* C = B + N0 * 32;     // x1 (N1x64), y0 (N0x32)

#define STATS(CH, X, NN) bn_stats<CH><<<P, 256, 0, stream>>>(X, part, (int)(NN))
#define FIN(GBI, GBFULL, GOFF, SL, CH, NN)                                           \
    bn_fin<<<1, 256, 0, stream>>>(part, (const float*)d_in[GBI], GBFULL, GOFF,       \
                                  ab + (SL) * 256, CH, P, 1.0 / (double)(NN))
#define AB(SL) (ab + (SL) * 256)
#define WF(I) ((const float*)d_in[I])

    // ---- level 0 ----
    conv_in<<<(int)((N0 + 255) / 256), 256, 0, stream>>>(
        feat, nbr0, WF(1), A, (int)N0);                                   // t0 -> A
    STATS(32, A, N0); FIN(2, 32, 0, 0, 32, N0);                           // bn1_0
    gconv2<32, 32, 128, 27, 256, 32, 4, false><<<(int)((N0 + 127) / 128), 256, 0, stream>>>(
        A, nbr0, WF(3), 0, AB(0), B, (int)N0);                            // x0 -> B
    STATS(32, B, N0); FIN(4, 32, 0, 1, 32, N0);                           // bnd_0
    gconv2<32, 64, 64, 8, 256, 32, 4, false><<<(int)((N1 + 63) / 64), 256, 0, stream>>>(
        B, rb0, WF(5), 0, AB(1), A, (int)N1);                             // d0 -> A

    // ---- level 1 ----
    STATS(64, A, N1); FIN(6, 64, 0, 2, 64, N1);                           // bn1_1
    gconv2<64, 64, 64, 27, 256, 64, 4, false><<<(int)((N1 + 63) / 64), 256, 0, stream>>>(
        A, nbr1, WF(7), 0, AB(2), C, (int)N1);                            // x1 -> C
    STATS(64, C, N1); FIN(8, 64, 0, 3, 64, N1);                           // bnd_1
    gconv<64, 96, 8, 2, 4, 64, true, false><<<(int)((N2 + 7) / 8), 192, 0, stream>>>(
        C, rb1, WF(9), 0, AB(3), A, (int)N2);                             // d1 -> A

    // ---- level 2 ----
    STATS(96, A, N2); FIN(10, 96, 0, 4, 96, N2);                          // bn1_2
    gconv2<96, 96, 32, 27, 192, 96, 2, false><<<(int)((N2 + 31) / 32), 192, 0, stream>>>(
        A, nbr2, WF(11), 0, AB(4), D, (int)N2);                           // x2 -> D
    STATS(96, D, N2); FIN(12, 96, 0, 5, 96, N2);                          // bnu_1

    // ---- up to level 1 (concat channel-separable) ----
    upconv2<96, 64, 64, 256><<<(int)((N2 + 63) / 64), 256, 0, stream>>>(
        D, rb1, WF(13), AB(5), A, (int)N2);                               // u1 -> A
    STATS(64, C, N1); FIN(14, 128, 0, 6, 64, N1);                         // bn2_1 [x1]
    STATS(64, A, N1); FIN(14, 128, 64, 7, 64, N1);                        // bn2_1 [u1]
    gconv2<64, 64, 64, 27, 256, 128, 4, false><<<(int)((N1 + 63) / 64), 256, 0, stream>>>(
        C, nbr1, WF(15), 0, AB(6), D, (int)N1);                           // y1 p1 -> D
    gconv2<64, 64, 64, 27, 256, 128, 4, true><<<(int)((N1 + 63) / 64), 256, 0, stream>>>(
        A, nbr1, WF(15), 64, AB(7), D, (int)N1);                          // y1 += p2
    STATS(64, D, N1); FIN(16, 64, 0, 8, 64, N1);                          // bnu_0

    // ---- up to level 0 ----
    upconv2<64, 32, 128, 256><<<(int)((N1 + 127) / 128), 256, 0, stream>>>(
        D, rb0, WF(17), AB(8), A, (int)N1);                               // u0 -> A
    STATS(32, B, N0); FIN(18, 64, 0, 9, 32, N0);                          // bn2_0 [x0]
    STATS(32, A, N0); FIN(18, 64, 32, 10, 32, N0);                        // bn2_0 [u0]
    gconv2<32, 32, 128, 27, 256, 64, 4, false><<<(int)((N0 + 127) / 128), 256, 0, stream>>>(
        B, nbr0, WF(19), 0, AB(9), C, (int)N0);                           // y0 p1 -> C
    gconv2<32, 32, 128, 27, 256, 64, 4, true><<<(int)((N0 + 127) / 128), 256, 0, stream>>>(
        A, nbr0, WF(19), 32, AB(10), C, (int)N0);                         // y0 += p2
    STATS(32, C, N0); FIN(20, 32, 0, 11, 32, N0);                         // bnf

    final_k<<<(int)((N0 + 255) / 256), 256, 0, stream>>>(
        C, AB(11), WF(21), WF(22), (float*)d_out, (int)N0);

#undef STATS
#undef FIN
#undef AB
#undef WF
}